// Round 6
// baseline (432.191 us; speedup 1.0000x reference)
//
#include <hip/hip_runtime.h>
#include <hip/hip_cooperative_groups.h>
#include <math.h>

namespace cg = cooperative_groups;

#define N_NODES 100000
#define N_EDGES 1600000
#define DF      128
#define D_HEAD  64

#define NWIN    256
#define WIN_SZ  391            // 256*391 = 100096 >= N_NODES
#define NSEG    8              // pairs segment per blockIdx%8 (XCD hint)
#define CAP_SEG 1024           // per (segment,window): mean 781 + ~8.7 sigma
#define EPB     (N_EDGES / NWIN)   // 6250 edges per prep block (exact)
#define EITER   ((EPB + 255) / 256) // 25

typedef __attribute__((ext_vector_type(8))) short bf16x8;
typedef __attribute__((ext_vector_type(4))) float f32x4;

static __device__ __forceinline__ float mish_f(float v) {
    float e = __expf(v);
    float q = 1.0f + e;
    float p = q * q;
    float m = v * (p - 1.0f) / (p + 1.0f);
    return (v > 40.0f) ? v : m;   // guard fp32 overflow of p
}

static __device__ __forceinline__ unsigned short f2bf(float f) {
    unsigned int u = __builtin_bit_cast(unsigned int, f);
    unsigned int r = (u + 0x7fffu + ((u >> 16) & 1u)) >> 16;   // RNE
    return (unsigned short)r;
}

// ================= ONE cooperative prep kernel: zero -> bucket+cvt -> build =================
// 256 blocks (1/CU, co-resident: 43 KB LDS, low VGPR). Replaces zero_cnt + cvt_bucket +
// build_win (3 launches + bubbles). Phase order: [zero] sync [bucket scatter + streaming
// cvt rides behind it] fence+sync [per-window CSR build].

__global__ __launch_bounds__(256) void prep_kernel(
        const float* __restrict__ x,
        const float* __restrict__ Wl0, const float* __restrict__ Wr0,
        const float* __restrict__ Wl1, const float* __restrict__ Wr1,
        const float* __restrict__ Wh,
        const int* __restrict__ src, const int* __restrict__ dst,
        unsigned short* __restrict__ xb, unsigned short* __restrict__ wb,
        int* __restrict__ bucket_cnt, unsigned int* __restrict__ pairs,
        int* __restrict__ rowstart, int* __restrict__ csr) {
    __shared__ int cnt[NWIN][4];
    __shared__ int cur[NWIN][4];
    __shared__ int ldeg[WIN_SZ];
    __shared__ int lcsr[NSEG * CAP_SEG];
    __shared__ int tot[NWIN];
    __shared__ int wsum[4];
    __shared__ int red[4];

    cg::grid_group grid = cg::this_grid();
    int b   = blockIdx.x;
    int tid = threadIdx.x;

    // ---- phase 0: zero the segmented counters ----
    if (b < NSEG) bucket_cnt[b * NWIN + tid] = 0;
    grid.sync();

    // ---- phase 1: bucket this block's 6250 edges ----
    int set = tid & 3;
    int sg  = b & 7;
    int e0  = b * EPB;
    for (int i = tid; i < NWIN * 4; i += 256) ((int*)cnt)[i] = 0;
    __syncthreads();

    int dc[EITER];
    #pragma unroll
    for (int i = 0; i < EITER; ++i) {
        int e = e0 + tid + i * 256;
        int d = (e < e0 + EPB) ? dst[e] : -1;
        dc[i] = d;
        if (d >= 0) atomicAdd(&cnt[d / WIN_SZ][set], 1);
    }
    __syncthreads();
    {
        int w = tid;   // NWIN == 256: one window per thread
        int c0 = cnt[w][0], c1 = cnt[w][1], c2 = cnt[w][2], c3 = cnt[w][3];
        int base = atomicAdd(&bucket_cnt[sg * NWIN + w], c0 + c1 + c2 + c3);
        cur[w][0] = base;
        cur[w][1] = base + c0;
        cur[w][2] = base + c0 + c1;
        cur[w][3] = base + c0 + c1 + c2;
    }
    __syncthreads();
    #pragma unroll
    for (int i = 0; i < EITER; ++i) {
        int d = dc[i];
        if (d >= 0) {
            int e  = e0 + tid + i * 256;
            int s  = src[e];
            int w  = d / WIN_SZ;
            int dl = d - w * WIN_SZ;
            int idx = atomicAdd(&cur[w][set], 1);
            if (idx < CAP_SEG)
                pairs[((size_t)sg * NWIN + w) * CAP_SEG + idx] = (unsigned)s | ((unsigned)dl << 17);
        }
    }

    // ---- phase 2: streaming cvt (x + weights -> bf16), grid-stride ----
    {
        const int TT = NWIN * 256;           // 65536 threads
        int gtid = b * 256 + tid;
        for (int i = gtid; i < N_NODES * DF / 4; i += TT) {
            float4 v = ((const float4*)x)[i];
            ushort4 o;
            o.x = f2bf(v.x); o.y = f2bf(v.y); o.z = f2bf(v.z); o.w = f2bf(v.w);
            ((ushort4*)xb)[i] = o;
        }
        for (int id = gtid; id < 65536 + 8192; id += TT) {
            if (id < 65536) {
                int seg = id >> 14;
                int r   = id & 16383;
                const float* W = (seg == 0) ? Wl0 : (seg == 1) ? Wr0 : (seg == 2) ? Wl1 : Wr1;
                wb[id] = f2bf(W[r]);
            } else {
                wb[id] = f2bf(Wh[id - 65536]);
            }
        }
    }

    __threadfence();   // device-scope: pairs/bucket_cnt visible across XCDs
    grid.sync();

    // ---- phase 3: build CSR for window w = blockIdx.x ----
    int w = b;
    int base_node = w * WIN_SZ;
    int nn = N_NODES - base_node;
    if (nn > WIN_SZ) nn = WIN_SZ;
    if (nn < 0) nn = 0;

    {
        int t = 0;
        #pragma unroll
        for (int s2 = 0; s2 < NSEG; ++s2) {
            int c = bucket_cnt[s2 * NWIN + tid];
            t += (c > CAP_SEG) ? CAP_SEG : c;
        }
        tot[tid] = t;
    }
    for (int i = tid; i < WIN_SZ; i += 256) ldeg[i] = 0;
    __syncthreads();

    int val = (tid < w) ? tot[tid] : 0;
    #pragma unroll
    for (int o = 32; o; o >>= 1) val += __shfl_xor(val, o);
    if ((tid & 63) == 0) red[tid >> 6] = val;
    int ntot = tot[w];
    __syncthreads();
    int ebase = red[0] + red[1] + red[2] + red[3];

    #pragma unroll
    for (int s2 = 0; s2 < NSEG; ++s2) {
        int c = bucket_cnt[s2 * NWIN + w];
        if (c > CAP_SEG) c = CAP_SEG;
        const unsigned int* pw = pairs + ((size_t)s2 * NWIN + w) * CAP_SEG;
        for (int i = tid; i < c; i += 256)
            atomicAdd(&ldeg[pw[i] >> 17], 1);
    }
    __syncthreads();

    int i0 = tid * 2;
    int v[2];
    int s = 0;
    #pragma unroll
    for (int q = 0; q < 2; ++q) {
        v[q] = (i0 + q < nn) ? ldeg[i0 + q] : 0;
        s += v[q];
    }
    int lane = tid & 63, wv = tid >> 6;
    int sc = s;
    #pragma unroll
    for (int d = 1; d < 64; d <<= 1) {
        int t = __shfl_up(sc, d);
        if (lane >= d) sc += t;
    }
    if (lane == 63) wsum[wv] = sc;
    __syncthreads();
    int woff = 0;
    for (int q = 0; q < wv; ++q) woff += wsum[q];
    int run = woff + sc - s;
    #pragma unroll
    for (int q = 0; q < 2; ++q) {
        if (i0 + q < nn) {
            rowstart[base_node + i0 + q] = ebase + run;
            ldeg[i0 + q] = run;
            run += v[q];
        }
    }
    if (w == NWIN - 1 && tid == 0) rowstart[N_NODES] = N_EDGES;
    __syncthreads();

    #pragma unroll
    for (int s2 = 0; s2 < NSEG; ++s2) {
        int c = bucket_cnt[s2 * NWIN + w];
        if (c > CAP_SEG) c = CAP_SEG;
        const unsigned int* pw = pairs + ((size_t)s2 * NWIN + w) * CAP_SEG;
        for (int i = tid; i < c; i += 256) {
            unsigned int p = pw[i];
            int slot = atomicAdd(&ldeg[p >> 17], 1);
            lcsr[slot] = (int)(p & 0x1FFFFu);
        }
    }
    __syncthreads();

    for (int i = tid; i < ntot; i += 256)
        csr[ebase + i] = lcsr[i];
}

// ---------------- mean aggregation: 2 nodes per wave (r5, at gather roofline) ----------

__global__ __launch_bounds__(256) void aggregate_kernel(const unsigned short* __restrict__ X,
                                                        const int* __restrict__ rowstart,
                                                        const int* __restrict__ csr,
                                                        unsigned short* __restrict__ out) {
    int wv   = threadIdx.x >> 6;
    int lane = threadIdx.x & 63;
    int slot = lane >> 4;
    int l16  = lane & 15;
    int wid  = blockIdx.x * 4 + wv;          // 0..49999
    int n0 = wid;
    int n1 = wid + (N_NODES / 2);

    int a0 = rowstart[n0], a1 = rowstart[n0 + 1];
    int b0 = rowstart[n1], b1 = rowstart[n1 + 1];

    int ca[4], cb[4];
    #pragma unroll
    for (int j = 0; j < 4; ++j) {
        int ea = a0 + 4 * j + slot;
        int eb = b0 + 4 * j + slot;
        ca[j] = (ea < a1) ? csr[ea] : -1;
        cb[j] = (eb < b1) ? csr[eb] : -1;
    }
    uint4 va[4], vb[4];
    #pragma unroll
    for (int j = 0; j < 4; ++j) {
        uint4 t = {0u, 0u, 0u, 0u};
        if (ca[j] >= 0) t = *(const uint4*)(X + (size_t)ca[j] * DF + l16 * 8);
        va[j] = t;
    }
    #pragma unroll
    for (int j = 0; j < 4; ++j) {
        uint4 t = {0u, 0u, 0u, 0u};
        if (cb[j] >= 0) t = *(const uint4*)(X + (size_t)cb[j] * DF + l16 * 8);
        vb[j] = t;
    }

    float accA[8], accB[8];
    #pragma unroll
    for (int i = 0; i < 8; ++i) { accA[i] = 0.f; accB[i] = 0.f; }

    #pragma unroll
    for (int j = 0; j < 4; ++j) {
        unsigned int w0[4] = {va[j].x, va[j].y, va[j].z, va[j].w};
        #pragma unroll
        for (int i = 0; i < 4; ++i) {
            accA[2 * i]     += __builtin_bit_cast(float, w0[i] << 16);
            accA[2 * i + 1] += __builtin_bit_cast(float, w0[i] & 0xffff0000u);
        }
    }
    #pragma unroll
    for (int j = 0; j < 4; ++j) {
        unsigned int w0[4] = {vb[j].x, vb[j].y, vb[j].z, vb[j].w};
        #pragma unroll
        for (int i = 0; i < 4; ++i) {
            accB[2 * i]     += __builtin_bit_cast(float, w0[i] << 16);
            accB[2 * i + 1] += __builtin_bit_cast(float, w0[i] & 0xffff0000u);
        }
    }

    for (int e0 = a0 + 16; e0 < a1; e0 += 16) {
        uint4 v[4];
        #pragma unroll
        for (int j = 0; j < 4; ++j) {
            int e = e0 + 4 * j + slot;
            uint4 t = {0u, 0u, 0u, 0u};
            if (e < a1) t = *(const uint4*)(X + (size_t)csr[e] * DF + l16 * 8);
            v[j] = t;
        }
        #pragma unroll
        for (int j = 0; j < 4; ++j) {
            unsigned int w0[4] = {v[j].x, v[j].y, v[j].z, v[j].w};
            #pragma unroll
            for (int i = 0; i < 4; ++i) {
                accA[2 * i]     += __builtin_bit_cast(float, w0[i] << 16);
                accA[2 * i + 1] += __builtin_bit_cast(float, w0[i] & 0xffff0000u);
            }
        }
    }
    for (int e0 = b0 + 16; e0 < b1; e0 += 16) {
        uint4 v[4];
        #pragma unroll
        for (int j = 0; j < 4; ++j) {
            int e = e0 + 4 * j + slot;
            uint4 t = {0u, 0u, 0u, 0u};
            if (e < b1) t = *(const uint4*)(X + (size_t)csr[e] * DF + l16 * 8);
            v[j] = t;
        }
        #pragma unroll
        for (int j = 0; j < 4; ++j) {
            unsigned int w0[4] = {v[j].x, v[j].y, v[j].z, v[j].w};
            #pragma unroll
            for (int i = 0; i < 4; ++i) {
                accB[2 * i]     += __builtin_bit_cast(float, w0[i] << 16);
                accB[2 * i + 1] += __builtin_bit_cast(float, w0[i] & 0xffff0000u);
            }
        }
    }

    #pragma unroll
    for (int i = 0; i < 8; ++i) {
        accA[i] += __shfl_xor(accA[i], 32);
        accA[i] += __shfl_xor(accA[i], 16);
        accB[i] += __shfl_xor(accB[i], 32);
        accB[i] += __shfl_xor(accB[i], 16);
    }

    int dA = a1 - a0, dB = b1 - b0;
    float invA = 1.0f / (float)(dA > 0 ? dA : 1);
    float invB = 1.0f / (float)(dB > 0 ? dB : 1);
    if (slot == 0) {
        unsigned int r[4];
        #pragma unroll
        for (int i = 0; i < 4; ++i) {
            unsigned int lo = f2bf(accA[2 * i] * invA);
            unsigned int hi = f2bf(accA[2 * i + 1] * invA);
            r[i] = lo | (hi << 16);
        }
        uint4 o = {r[0], r[1], r[2], r[3]};
        *(uint4*)(out + (size_t)n0 * DF + l16 * 8) = o;
    } else if (slot == 1) {
        unsigned int r[4];
        #pragma unroll
        for (int i = 0; i < 4; ++i) {
            unsigned int lo = f2bf(accB[2 * i] * invB);
            unsigned int hi = f2bf(accB[2 * i + 1] * invB);
            r[i] = lo | (hi << 16);
        }
        uint4 o = {r[0], r[1], r[2], r[3]};
        *(uint4*)(out + (size_t)n1 * DF + l16 * 8) = o;
    }
}

// ---------------- MFMA GEMM (layer 0): out = mish([A|H] @ [Wl^T; Wr^T] + bias) -------

template <int COLS, bool TWO, bool MISH, bool OUT_BF16>
__global__ __launch_bounds__(256, 3) void sage_gemm(const unsigned short* __restrict__ A,
                                                    const unsigned short* __restrict__ H,
                                                    const unsigned short* __restrict__ Wl,
                                                    const unsigned short* __restrict__ Wr,
                                                    const float* __restrict__ bias,
                                                    void* __restrict__ out) {
    constexpr int NT  = COLS / 16;
    constexpr int LDA = 136;
    __shared__ unsigned short Ws[COLS * LDA];

    int tid  = threadIdx.x;
    int wv   = tid >> 6;
    int lane = tid & 63;
    int quad = lane >> 4;
    int l16  = lane & 15;
    int m0   = blockIdx.x * 128;

    int arow0 = m0 + wv * 32 + l16;
    int arow1 = arow0 + 16;
    if (arow0 > N_NODES - 1) arow0 = N_NODES - 1;
    if (arow1 > N_NODES - 1) arow1 = N_NODES - 1;

    f32x4 acc[2][NT];
    #pragma unroll
    for (int t = 0; t < 2; ++t)
        #pragma unroll
        for (int n = 0; n < NT; ++n) acc[t][n] = (f32x4){0.f, 0.f, 0.f, 0.f};

    #pragma unroll
    for (int phase = 0; phase < (TWO ? 2 : 1); ++phase) {
        const unsigned short* Ain = phase ? H : A;
        const unsigned short* Win = phase ? Wr : Wl;
        if (phase) __syncthreads();
        #pragma unroll
        for (int i = 0; i < COLS / 16; ++i) {
            int idx = tid + i * 256;
            int r   = idx >> 4;
            int cb  = (idx & 15) * 8;
            *(uint4*)&Ws[r * LDA + cb] = *(const uint4*)&Win[r * 128 + cb];
        }
        __syncthreads();

        const unsigned short* Ap0 = Ain + (size_t)arow0 * 128 + quad * 8;
        const unsigned short* Ap1 = Ain + (size_t)arow1 * 128 + quad * 8;
        #pragma unroll
        for (int ks = 0; ks < 4; ++ks) {
            bf16x8 af0 = *(const bf16x8*)(Ap0 + ks * 32);
            bf16x8 af1 = *(const bf16x8*)(Ap1 + ks * 32);
            #pragma unroll
            for (int n = 0; n < NT; ++n) {
                bf16x8 bfr = *(const bf16x8*)&Ws[(n * 16 + l16) * LDA + ks * 32 + quad * 8];
                acc[0][n] = __builtin_amdgcn_mfma_f32_16x16x32_bf16(af0, bfr, acc[0][n], 0, 0, 0);
                acc[1][n] = __builtin_amdgcn_mfma_f32_16x16x32_bf16(af1, bfr, acc[1][n], 0, 0, 0);
            }
        }
    }

    #pragma unroll
    for (int t = 0; t < 2; ++t) {
        #pragma unroll
        for (int n = 0; n < NT; ++n) {
            int col = n * 16 + l16;
            float b = bias[col];
            #pragma unroll
            for (int r = 0; r < 4; ++r) {
                int row = m0 + wv * 32 + t * 16 + quad * 4 + r;
                if (row < N_NODES) {
                    float v = acc[t][n][r] + b;
                    if constexpr (MISH) v = mish_f(v);
                    if constexpr (OUT_BF16)
                        ((unsigned short*)out)[(size_t)row * COLS + col] = f2bf(v);
                    else
                        ((float*)out)[(size_t)row * COLS + col] = v;
                }
            }
        }
    }
}

// ---------------- layer 1 + head fused: out = (mish(gemm1) @ Wh^T + bh) --------------

__global__ __launch_bounds__(256, 3) void sage_gemm1_head(const unsigned short* __restrict__ A,
                                                          const unsigned short* __restrict__ H,
                                                          const unsigned short* __restrict__ Wl,
                                                          const unsigned short* __restrict__ Wr,
                                                          const float* __restrict__ bias,
                                                          const unsigned short* __restrict__ Wh,
                                                          const float* __restrict__ bh,
                                                          float* __restrict__ out) {
    constexpr int LDA = 136;
    __shared__ unsigned short Ws[128 * LDA];

    int tid  = threadIdx.x;
    int wv   = tid >> 6;
    int lane = tid & 63;
    int quad = lane >> 4;
    int l16  = lane & 15;
    int m0   = blockIdx.x * 128;

    int arow0 = m0 + wv * 32 + l16;
    int arow1 = arow0 + 16;
    if (arow0 > N_NODES - 1) arow0 = N_NODES - 1;
    if (arow1 > N_NODES - 1) arow1 = N_NODES - 1;

    f32x4 acc0[2][8];
    #pragma unroll
    for (int t = 0; t < 2; ++t)
        #pragma unroll
        for (int n = 0; n < 8; ++n) acc0[t][n] = (f32x4){0.f, 0.f, 0.f, 0.f};

    #pragma unroll
    for (int phase = 0; phase < 2; ++phase) {
        const unsigned short* Ain = phase ? H : A;
        const unsigned short* Win = phase ? Wr : Wl;
        if (phase) __syncthreads();
        #pragma unroll
        for (int i = 0; i < 8; ++i) {
            int idx = tid + i * 256;
            int r   = idx >> 4;
            int cb  = (idx & 15) * 8;
            *(uint4*)&Ws[r * LDA + cb] = *(const uint4*)&Win[r * 128 + cb];
        }
        __syncthreads();

        const unsigned short* Ap0 = Ain + (size_t)arow0 * 128 + quad * 8;
        const unsigned short* Ap1 = Ain + (size_t)arow1 * 128 + quad * 8;
        #pragma unroll
        for (int ks = 0; ks < 4; ++ks) {
            bf16x8 af0 = *(const bf16x8*)(Ap0 + ks * 32);
            bf16x8 af1 = *(const bf16x8*)(Ap1 + ks * 32);
            #pragma unroll
            for (int n = 0; n < 8; ++n) {
                bf16x8 bfr = *(const bf16x8*)&Ws[(n * 16 + l16) * LDA + ks * 32 + quad * 8];
                acc0[0][n] = __builtin_amdgcn_mfma_f32_16x16x32_bf16(af0, bfr, acc0[0][n], 0, 0, 0);
                acc0[1][n] = __builtin_amdgcn_mfma_f32_16x16x32_bf16(af1, bfr, acc0[1][n], 0, 0, 0);
            }
        }
    }
    __syncthreads();

    #pragma unroll
    for (int t = 0; t < 2; ++t) {
        #pragma unroll
        for (int n = 0; n < 8; ++n) {
            int col = n * 16 + l16;
            float b = bias[col];
            #pragma unroll
            for (int r = 0; r < 4; ++r) {
                int row = wv * 32 + t * 16 + quad * 4 + r;   // local tile row
                Ws[row * LDA + col] = f2bf(mish_f(acc0[t][n][r] + b));
            }
        }
    }
    __syncthreads();

    f32x4 acc2[2][4];
    #pragma unroll
    for (int t = 0; t < 2; ++t)
        #pragma unroll
        for (int n = 0; n < 4; ++n) acc2[t][n] = (f32x4){0.f, 0.f, 0.f, 0.f};

    int ar0 = wv * 32 + l16;
    #pragma unroll
    for (int ks = 0; ks < 4; ++ks) {
        bf16x8 af0 = *(const bf16x8*)&Ws[ar0 * LDA + ks * 32 + quad * 8];
        bf16x8 af1 = *(const bf16x8*)&Ws[(ar0 + 16) * LDA + ks * 32 + quad * 8];
        #pragma unroll
        for (int n = 0; n < 4; ++n) {
            bf16x8 bfr = *(const bf16x8*)&Wh[(n * 16 + l16) * 128 + ks * 32 + quad * 8];
            acc2[0][n] = __builtin_amdgcn_mfma_f32_16x16x32_bf16(af0, bfr, acc2[0][n], 0, 0, 0);
            acc2[1][n] = __builtin_amdgcn_mfma_f32_16x16x32_bf16(af1, bfr, acc2[1][n], 0, 0, 0);
        }
    }

    #pragma unroll
    for (int t = 0; t < 2; ++t) {
        #pragma unroll
        for (int n = 0; n < 4; ++n) {
            int col = n * 16 + l16;
            float b = bh[col];
            #pragma unroll
            for (int r = 0; r < 4; ++r) {
                int row = m0 + wv * 32 + t * 16 + quad * 4 + r;
                if (row < N_NODES)
                    out[(size_t)row * D_HEAD + col] = acc2[t][n][r] + b;
            }
        }
    }
}

// ---------------- launch ----------------

extern "C" void kernel_launch(void* const* d_in, const int* in_sizes, int n_in,
                              void* d_out, int out_size, void* d_ws, size_t ws_size,
                              hipStream_t stream) {
    const float* x   = (const float*)d_in[0];
    const int*   ei  = (const int*)d_in[1];
    const float* Wl0 = (const float*)d_in[2];
    const float* bl0 = (const float*)d_in[3];
    const float* Wr0 = (const float*)d_in[4];
    const float* Wl1 = (const float*)d_in[5];
    const float* bl1 = (const float*)d_in[6];
    const float* Wr1 = (const float*)d_in[7];
    const float* Wh  = (const float*)d_in[8];
    const float* bh  = (const float*)d_in[9];
    float* out = (float*)d_out;

    const int* src = ei;
    const int* dst = ei + N_EDGES;

    char* ws = (char*)d_ws;
    size_t off = 0;
    auto alloc = [&](size_t bytes) -> void* {
        void* p = ws + off;
        off += (bytes + 255) & ~(size_t)255;
        return p;
    };
    int* rowstart   = (int*)alloc((N_NODES + 1) * 4);
    int* csr        = (int*)alloc(N_EDGES * 4);
    int* bucket_cnt = (int*)alloc(NSEG * NWIN * 4);

    unsigned short* Wb  = (unsigned short*)alloc((size_t)(65536 + 8192) * 2);
    unsigned short* Xb  = (unsigned short*)alloc((size_t)N_NODES * DF * 2);
    unsigned short* Ab  = (unsigned short*)alloc((size_t)N_NODES * DF * 2);
    unsigned short* H1b = (unsigned short*)alloc((size_t)N_NODES * DF * 2);

    unsigned short* Wlb0 = Wb;
    unsigned short* Wrb0 = Wb + 16384;
    unsigned short* Wlb1 = Wb + 32768;
    unsigned short* Wrb1 = Wb + 49152;
    unsigned short* Whb  = Wb + 65536;
    unsigned int* pairs  = (unsigned int*)H1b; // 8.4 MB, aliased: dead before gemm0 writes H1b

    unsigned short* xb = Xb;
    unsigned short* wb = Wb;
    void* args[] = {
        (void*)&x, (void*)&Wl0, (void*)&Wr0, (void*)&Wl1, (void*)&Wr1, (void*)&Wh,
        (void*)&src, (void*)&dst, (void*)&xb, (void*)&wb,
        (void*)&bucket_cnt, (void*)&pairs, (void*)&rowstart, (void*)&csr
    };
    hipLaunchCooperativeKernel((const void*)prep_kernel, dim3(NWIN), dim3(256),
                               args, 0, stream);

    // layer 0  (aggregate: 2 nodes per wave -> grid = N/8 blocks)
    aggregate_kernel<<<N_NODES / 8, 256, 0, stream>>>(Xb, rowstart, csr, Ab);
    const int grid = (N_NODES + 127) / 128;
    sage_gemm<128, true, true, true><<<grid, 256, 0, stream>>>(Ab, Xb, Wlb0, Wrb0, bl0, H1b);
    // layer 1 + head fused
    aggregate_kernel<<<N_NODES / 8, 256, 0, stream>>>(H1b, rowstart, csr, Ab);
    sage_gemm1_head<<<grid, 256, 0, stream>>>(Ab, H1b, Wlb1, Wrb1, bl1, Whb, bh, out);
}

// Round 7
// 320.172 us; speedup vs baseline: 1.3499x; 1.3499x over previous
//
#include <hip/hip_runtime.h>
#include <math.h>

#define N_NODES 100000
#define N_EDGES 1600000
#define DF      128
#define D_HEAD  64

#define NWIN    1024
#define WIN_SZ  98             // 1024*98 = 100352 >= N_NODES
#define NSEG    8              // pairs segment per bucket-block %8 (XCD hint)
#define CAP_SEG 320            // per (segment,window): mean 195 + ~9 sigma
#define NSET    2              // LDS counter sets in bucket
#define BCH     2048           // edges per bucket block (small -> ~3 blocks/CU, latency hidden)
#define NBUCK   ((N_EDGES + BCH - 1) / BCH)   // 782

typedef __attribute__((ext_vector_type(8))) short bf16x8;
typedef __attribute__((ext_vector_type(4))) float f32x4;

static __device__ __forceinline__ float mish_f(float v) {
    float e = __expf(v);
    float q = 1.0f + e;
    float p = q * q;
    float m = v * (p - 1.0f) / (p + 1.0f);
    return (v > 40.0f) ? v : m;   // guard fp32 overflow of p
}

static __device__ __forceinline__ unsigned short f2bf(float f) {
    unsigned int u = __builtin_bit_cast(unsigned int, f);
    unsigned int r = (u + 0x7fffu + ((u >> 16) & 1u)) >> 16;   // RNE
    return (unsigned short)r;
}

// ---------------- zero bucket counters (graph-capture-safe) ----------------

__global__ void zero_cnt_kernel(int* __restrict__ bucket_cnt) {
    bucket_cnt[blockIdx.x * 256 + threadIdx.x] = 0;   // <<<NSEG*NWIN/256, 256>>>
}

// ---------------- merged cvt (x + weights -> bf16) + bucket (edge partition) ----------
// Bucket blocks are SMALL (2048 edges) so ~3/CU run concurrently with the streaming cvt
// blocks -> the scatter's latency hides under cvt's BW phase (r6 lesson: prep phases die
// at 1 block/CU). Reservation atomics: ~700K skip-zero-guarded, L2-side, ~5 us.

#define XB 12500   // (N_NODES*DF/4)/256 blocks for x
#define WB 288     // (65536+8192)/256 blocks for weights

__global__ __launch_bounds__(256) void cvt_bucket_kernel(
        const float* __restrict__ x,
        const float* __restrict__ Wl0, const float* __restrict__ Wr0,
        const float* __restrict__ Wl1, const float* __restrict__ Wr1,
        const float* __restrict__ Wh,
        const int* __restrict__ src, const int* __restrict__ dst,
        unsigned short* __restrict__ xb, unsigned short* __restrict__ wb,
        int* __restrict__ bucket_cnt, unsigned int* __restrict__ pairs) {
    __shared__ int cnt[NWIN][NSET];
    __shared__ int cur[NWIN][NSET];
    int b   = blockIdx.x;
    int tid = threadIdx.x;

    if (b >= NBUCK) {
        int cb = b - NBUCK;
        if (cb < XB) {
            int i = cb * 256 + tid;
            float4 v = ((const float4*)x)[i];
            ushort4 o;
            o.x = f2bf(v.x); o.y = f2bf(v.y); o.z = f2bf(v.z); o.w = f2bf(v.w);
            ((ushort4*)xb)[i] = o;
        } else {
            int id = (cb - XB) * 256 + tid;
            if (id < 65536) {
                int seg = id >> 14;
                int r   = id & 16383;
                const float* W = (seg == 0) ? Wl0 : (seg == 1) ? Wr0 : (seg == 2) ? Wl1 : Wr1;
                wb[id] = f2bf(W[r]);
            } else {
                wb[id] = f2bf(Wh[id - 65536]);
            }
        }
        return;
    }

    // ---- bucket path: 2048 edges ----
    int set = tid & (NSET - 1);
    int sg  = b & 7;
    int e0  = b * BCH;
    for (int i = tid; i < NWIN * NSET; i += 256) ((int*)cnt)[i] = 0;
    __syncthreads();

    int dc[BCH / 256];   // 8
    #pragma unroll
    for (int i = 0; i < BCH / 256; ++i) {
        int e = e0 + tid + i * 256;
        int d = (e < N_EDGES) ? dst[e] : -1;
        dc[i] = d;
        if (d >= 0) atomicAdd(&cnt[d / WIN_SZ][set], 1);
    }
    __syncthreads();
    for (int w = tid; w < NWIN; w += 256) {
        int c0 = cnt[w][0], c1 = cnt[w][1];
        if (c0 + c1) {
            int base = atomicAdd(&bucket_cnt[sg * NWIN + w], c0 + c1);
            cur[w][0] = base;
            cur[w][1] = base + c0;
        }
    }
    __syncthreads();
    #pragma unroll
    for (int i = 0; i < BCH / 256; ++i) {
        int d = dc[i];
        if (d >= 0) {
            int e  = e0 + tid + i * 256;
            int s  = src[e];
            int w  = d / WIN_SZ;
            int dl = d - w * WIN_SZ;
            int idx = atomicAdd(&cur[w][set], 1);
            if (idx < CAP_SEG)
                pairs[((size_t)sg * NWIN + w) * CAP_SEG + idx] = (unsigned)s | ((unsigned)dl << 17);
        }
    }
}

// ---------------- per-window CSR build: histogram + scan + scatter in LDS ----------------
// NWIN=1024 -> 4 blocks/CU (was 256 -> 1/CU, latency-starved; r6 lesson). LDS ~14.7 KB.

__global__ __launch_bounds__(256) void build_win(const unsigned int* __restrict__ pairs,
                                                 const int* __restrict__ bucket_cnt,
                                                 int* __restrict__ rowstart,
                                                 int* __restrict__ csr) {
    __shared__ int tot[NWIN];              // 4 KB
    __shared__ int ldeg[WIN_SZ];
    __shared__ int lcsr[NSEG * CAP_SEG];   // 2560 ints = 10.2 KB
    __shared__ int wsum[4];
    __shared__ int red[4];

    int tid = threadIdx.x;
    int w   = blockIdx.x;
    int base_node = w * WIN_SZ;
    int nn = N_NODES - base_node;
    if (nn > WIN_SZ) nn = WIN_SZ;
    if (nn < 0) nn = 0;

    // per-window clamped totals: 4 windows per thread
    #pragma unroll
    for (int q = 0; q < 4; ++q) {
        int w4 = tid * 4 + q;
        int t = 0;
        #pragma unroll
        for (int s2 = 0; s2 < NSEG; ++s2) {
            int c = bucket_cnt[s2 * NWIN + w4];
            t += (c > CAP_SEG) ? CAP_SEG : c;
        }
        tot[w4] = t;
    }
    for (int i = tid; i < WIN_SZ; i += 256) ldeg[i] = 0;
    __syncthreads();

    // ebase = sum of tot[j] for j < w  (each thread contributes from its 4 windows)
    int part = 0;
    #pragma unroll
    for (int q = 0; q < 4; ++q) {
        int w4 = tid * 4 + q;
        if (w4 < w) part += tot[w4];
    }
    #pragma unroll
    for (int o = 32; o; o >>= 1) part += __shfl_xor(part, o);
    if ((tid & 63) == 0) red[tid >> 6] = part;
    int ntot = tot[w];
    __syncthreads();
    int ebase = red[0] + red[1] + red[2] + red[3];

    // histogram over the window's 8 segments
    #pragma unroll
    for (int s2 = 0; s2 < NSEG; ++s2) {
        int c = bucket_cnt[s2 * NWIN + w];
        if (c > CAP_SEG) c = CAP_SEG;
        const unsigned int* pw = pairs + ((size_t)s2 * NWIN + w) * CAP_SEG;
        for (int i = tid; i < c; i += 256)
            atomicAdd(&ldeg[pw[i] >> 17], 1);
    }
    __syncthreads();

    // exclusive scan over the window's nodes (2 per thread; only tid<49 active)
    int i0 = tid * 2;
    int v[2];
    int s = 0;
    #pragma unroll
    for (int q = 0; q < 2; ++q) {
        v[q] = (i0 + q < nn) ? ldeg[i0 + q] : 0;
        s += v[q];
    }
    int lane = tid & 63, wv = tid >> 6;
    int sc = s;
    #pragma unroll
    for (int d = 1; d < 64; d <<= 1) {
        int t = __shfl_up(sc, d);
        if (lane >= d) sc += t;
    }
    if (lane == 63) wsum[wv] = sc;
    __syncthreads();
    int woff = 0;
    for (int q = 0; q < wv; ++q) woff += wsum[q];
    int run = woff + sc - s;
    #pragma unroll
    for (int q = 0; q < 2; ++q) {
        if (i0 + q < nn) {
            rowstart[base_node + i0 + q] = ebase + run;
            ldeg[i0 + q] = run;
            run += v[q];
        }
    }
    if (w == NWIN - 1 && tid == 0) rowstart[N_NODES] = N_EDGES;
    __syncthreads();

    // scatter into dense lcsr[0..ntot)
    #pragma unroll
    for (int s2 = 0; s2 < NSEG; ++s2) {
        int c = bucket_cnt[s2 * NWIN + w];
        if (c > CAP_SEG) c = CAP_SEG;
        const unsigned int* pw = pairs + ((size_t)s2 * NWIN + w) * CAP_SEG;
        for (int i = tid; i < c; i += 256) {
            unsigned int p = pw[i];
            int slot = atomicAdd(&ldeg[p >> 17], 1);
            lcsr[slot] = (int)(p & 0x1FFFFu);
        }
    }
    __syncthreads();

    for (int i = tid; i < ntot; i += 256)
        csr[ebase + i] = lcsr[i];
}

// ---------------- mean aggregation: 2 nodes per wave (r5, at gather roofline) ----------

__global__ __launch_bounds__(256) void aggregate_kernel(const unsigned short* __restrict__ X,
                                                        const int* __restrict__ rowstart,
                                                        const int* __restrict__ csr,
                                                        unsigned short* __restrict__ out) {
    int wv   = threadIdx.x >> 6;
    int lane = threadIdx.x & 63;
    int slot = lane >> 4;
    int l16  = lane & 15;
    int wid  = blockIdx.x * 4 + wv;          // 0..49999
    int n0 = wid;
    int n1 = wid + (N_NODES / 2);

    int a0 = rowstart[n0], a1 = rowstart[n0 + 1];
    int b0 = rowstart[n1], b1 = rowstart[n1 + 1];

    int ca[4], cb[4];
    #pragma unroll
    for (int j = 0; j < 4; ++j) {
        int ea = a0 + 4 * j + slot;
        int eb = b0 + 4 * j + slot;
        ca[j] = (ea < a1) ? csr[ea] : -1;
        cb[j] = (eb < b1) ? csr[eb] : -1;
    }
    uint4 va[4], vb[4];
    #pragma unroll
    for (int j = 0; j < 4; ++j) {
        uint4 t = {0u, 0u, 0u, 0u};
        if (ca[j] >= 0) t = *(const uint4*)(X + (size_t)ca[j] * DF + l16 * 8);
        va[j] = t;
    }
    #pragma unroll
    for (int j = 0; j < 4; ++j) {
        uint4 t = {0u, 0u, 0u, 0u};
        if (cb[j] >= 0) t = *(const uint4*)(X + (size_t)cb[j] * DF + l16 * 8);
        vb[j] = t;
    }

    float accA[8], accB[8];
    #pragma unroll
    for (int i = 0; i < 8; ++i) { accA[i] = 0.f; accB[i] = 0.f; }

    #pragma unroll
    for (int j = 0; j < 4; ++j) {
        unsigned int w0[4] = {va[j].x, va[j].y, va[j].z, va[j].w};
        #pragma unroll
        for (int i = 0; i < 4; ++i) {
            accA[2 * i]     += __builtin_bit_cast(float, w0[i] << 16);
            accA[2 * i + 1] += __builtin_bit_cast(float, w0[i] & 0xffff0000u);
        }
    }
    #pragma unroll
    for (int j = 0; j < 4; ++j) {
        unsigned int w0[4] = {vb[j].x, vb[j].y, vb[j].z, vb[j].w};
        #pragma unroll
        for (int i = 0; i < 4; ++i) {
            accB[2 * i]     += __builtin_bit_cast(float, w0[i] << 16);
            accB[2 * i + 1] += __builtin_bit_cast(float, w0[i] & 0xffff0000u);
        }
    }

    for (int e0 = a0 + 16; e0 < a1; e0 += 16) {
        uint4 v[4];
        #pragma unroll
        for (int j = 0; j < 4; ++j) {
            int e = e0 + 4 * j + slot;
            uint4 t = {0u, 0u, 0u, 0u};
            if (e < a1) t = *(const uint4*)(X + (size_t)csr[e] * DF + l16 * 8);
            v[j] = t;
        }
        #pragma unroll
        for (int j = 0; j < 4; ++j) {
            unsigned int w0[4] = {v[j].x, v[j].y, v[j].z, v[j].w};
            #pragma unroll
            for (int i = 0; i < 4; ++i) {
                accA[2 * i]     += __builtin_bit_cast(float, w0[i] << 16);
                accA[2 * i + 1] += __builtin_bit_cast(float, w0[i] & 0xffff0000u);
            }
        }
    }
    for (int e0 = b0 + 16; e0 < b1; e0 += 16) {
        uint4 v[4];
        #pragma unroll
        for (int j = 0; j < 4; ++j) {
            int e = e0 + 4 * j + slot;
            uint4 t = {0u, 0u, 0u, 0u};
            if (e < b1) t = *(const uint4*)(X + (size_t)csr[e] * DF + l16 * 8);
            v[j] = t;
        }
        #pragma unroll
        for (int j = 0; j < 4; ++j) {
            unsigned int w0[4] = {v[j].x, v[j].y, v[j].z, v[j].w};
            #pragma unroll
            for (int i = 0; i < 4; ++i) {
                accB[2 * i]     += __builtin_bit_cast(float, w0[i] << 16);
                accB[2 * i + 1] += __builtin_bit_cast(float, w0[i] & 0xffff0000u);
            }
        }
    }

    #pragma unroll
    for (int i = 0; i < 8; ++i) {
        accA[i] += __shfl_xor(accA[i], 32);
        accA[i] += __shfl_xor(accA[i], 16);
        accB[i] += __shfl_xor(accB[i], 32);
        accB[i] += __shfl_xor(accB[i], 16);
    }

    int dA = a1 - a0, dB = b1 - b0;
    float invA = 1.0f / (float)(dA > 0 ? dA : 1);
    float invB = 1.0f / (float)(dB > 0 ? dB : 1);
    if (slot == 0) {
        unsigned int r[4];
        #pragma unroll
        for (int i = 0; i < 4; ++i) {
            unsigned int lo = f2bf(accA[2 * i] * invA);
            unsigned int hi = f2bf(accA[2 * i + 1] * invA);
            r[i] = lo | (hi << 16);
        }
        uint4 o = {r[0], r[1], r[2], r[3]};
        *(uint4*)(out + (size_t)n0 * DF + l16 * 8) = o;
    } else if (slot == 1) {
        unsigned int r[4];
        #pragma unroll
        for (int i = 0; i < 4; ++i) {
            unsigned int lo = f2bf(accB[2 * i] * invB);
            unsigned int hi = f2bf(accB[2 * i + 1] * invB);
            r[i] = lo | (hi << 16);
        }
        uint4 o = {r[0], r[1], r[2], r[3]};
        *(uint4*)(out + (size_t)n1 * DF + l16 * 8) = o;
    }
}

// ---------------- MFMA GEMM (layer 0): out = mish([A|H] @ [Wl^T; Wr^T] + bias) -------

template <int COLS, bool TWO, bool MISH, bool OUT_BF16>
__global__ __launch_bounds__(256, 3) void sage_gemm(const unsigned short* __restrict__ A,
                                                    const unsigned short* __restrict__ H,
                                                    const unsigned short* __restrict__ Wl,
                                                    const unsigned short* __restrict__ Wr,
                                                    const float* __restrict__ bias,
                                                    void* __restrict__ out) {
    constexpr int NT  = COLS / 16;
    constexpr int LDA = 136;
    __shared__ unsigned short Ws[COLS * LDA];

    int tid  = threadIdx.x;
    int wv   = tid >> 6;
    int lane = tid & 63;
    int quad = lane >> 4;
    int l16  = lane & 15;
    int m0   = blockIdx.x * 128;

    int arow0 = m0 + wv * 32 + l16;
    int arow1 = arow0 + 16;
    if (arow0 > N_NODES - 1) arow0 = N_NODES - 1;
    if (arow1 > N_NODES - 1) arow1 = N_NODES - 1;

    f32x4 acc[2][NT];
    #pragma unroll
    for (int t = 0; t < 2; ++t)
        #pragma unroll
        for (int n = 0; n < NT; ++n) acc[t][n] = (f32x4){0.f, 0.f, 0.f, 0.f};

    #pragma unroll
    for (int phase = 0; phase < (TWO ? 2 : 1); ++phase) {
        const unsigned short* Ain = phase ? H : A;
        const unsigned short* Win = phase ? Wr : Wl;
        if (phase) __syncthreads();
        #pragma unroll
        for (int i = 0; i < COLS / 16; ++i) {
            int idx = tid + i * 256;
            int r   = idx >> 4;
            int cb  = (idx & 15) * 8;
            *(uint4*)&Ws[r * LDA + cb] = *(const uint4*)&Win[r * 128 + cb];
        }
        __syncthreads();

        const unsigned short* Ap0 = Ain + (size_t)arow0 * 128 + quad * 8;
        const unsigned short* Ap1 = Ain + (size_t)arow1 * 128 + quad * 8;
        #pragma unroll
        for (int ks = 0; ks < 4; ++ks) {
            bf16x8 af0 = *(const bf16x8*)(Ap0 + ks * 32);
            bf16x8 af1 = *(const bf16x8*)(Ap1 + ks * 32);
            #pragma unroll
            for (int n = 0; n < NT; ++n) {
                bf16x8 bfr = *(const bf16x8*)&Ws[(n * 16 + l16) * LDA + ks * 32 + quad * 8];
                acc[0][n] = __builtin_amdgcn_mfma_f32_16x16x32_bf16(af0, bfr, acc[0][n], 0, 0, 0);
                acc[1][n] = __builtin_amdgcn_mfma_f32_16x16x32_bf16(af1, bfr, acc[1][n], 0, 0, 0);
            }
        }
    }

    #pragma unroll
    for (int t = 0; t < 2; ++t) {
        #pragma unroll
        for (int n = 0; n < NT; ++n) {
            int col = n * 16 + l16;
            float b = bias[col];
            #pragma unroll
            for (int r = 0; r < 4; ++r) {
                int row = m0 + wv * 32 + t * 16 + quad * 4 + r;
                if (row < N_NODES) {
                    float v = acc[t][n][r] + b;
                    if constexpr (MISH) v = mish_f(v);
                    if constexpr (OUT_BF16)
                        ((unsigned short*)out)[(size_t)row * COLS + col] = f2bf(v);
                    else
                        ((float*)out)[(size_t)row * COLS + col] = v;
                }
            }
        }
    }
}

// ---------------- layer 1 + head fused: out = (mish(gemm1) @ Wh^T + bh) --------------

__global__ __launch_bounds__(256, 3) void sage_gemm1_head(const unsigned short* __restrict__ A,
                                                          const unsigned short* __restrict__ H,
                                                          const unsigned short* __restrict__ Wl,
                                                          const unsigned short* __restrict__ Wr,
                                                          const float* __restrict__ bias,
                                                          const unsigned short* __restrict__ Wh,
                                                          const float* __restrict__ bh,
                                                          float* __restrict__ out) {
    constexpr int LDA = 136;
    __shared__ unsigned short Ws[128 * LDA];

    int tid  = threadIdx.x;
    int wv   = tid >> 6;
    int lane = tid & 63;
    int quad = lane >> 4;
    int l16  = lane & 15;
    int m0   = blockIdx.x * 128;

    int arow0 = m0 + wv * 32 + l16;
    int arow1 = arow0 + 16;
    if (arow0 > N_NODES - 1) arow0 = N_NODES - 1;
    if (arow1 > N_NODES - 1) arow1 = N_NODES - 1;

    f32x4 acc0[2][8];
    #pragma unroll
    for (int t = 0; t < 2; ++t)
        #pragma unroll
        for (int n = 0; n < 8; ++n) acc0[t][n] = (f32x4){0.f, 0.f, 0.f, 0.f};

    #pragma unroll
    for (int phase = 0; phase < 2; ++phase) {
        const unsigned short* Ain = phase ? H : A;
        const unsigned short* Win = phase ? Wr : Wl;
        if (phase) __syncthreads();
        #pragma unroll
        for (int i = 0; i < 8; ++i) {
            int idx = tid + i * 256;
            int r   = idx >> 4;
            int cb  = (idx & 15) * 8;
            *(uint4*)&Ws[r * LDA + cb] = *(const uint4*)&Win[r * 128 + cb];
        }
        __syncthreads();

        const unsigned short* Ap0 = Ain + (size_t)arow0 * 128 + quad * 8;
        const unsigned short* Ap1 = Ain + (size_t)arow1 * 128 + quad * 8;
        #pragma unroll
        for (int ks = 0; ks < 4; ++ks) {
            bf16x8 af0 = *(const bf16x8*)(Ap0 + ks * 32);
            bf16x8 af1 = *(const bf16x8*)(Ap1 + ks * 32);
            #pragma unroll
            for (int n = 0; n < 8; ++n) {
                bf16x8 bfr = *(const bf16x8*)&Ws[(n * 16 + l16) * LDA + ks * 32 + quad * 8];
                acc0[0][n] = __builtin_amdgcn_mfma_f32_16x16x32_bf16(af0, bfr, acc0[0][n], 0, 0, 0);
                acc0[1][n] = __builtin_amdgcn_mfma_f32_16x16x32_bf16(af1, bfr, acc0[1][n], 0, 0, 0);
            }
        }
    }
    __syncthreads();

    #pragma unroll
    for (int t = 0; t < 2; ++t) {
        #pragma unroll
        for (int n = 0; n < 8; ++n) {
            int col = n * 16 + l16;
            float b = bias[col];
            #pragma unroll
            for (int r = 0; r < 4; ++r) {
                int row = wv * 32 + t * 16 + quad * 4 + r;   // local tile row
                Ws[row * LDA + col] = f2bf(mish_f(acc0[t][n][r] + b));
            }
        }
    }
    __syncthreads();

    f32x4 acc2[2][4];
    #pragma unroll
    for (int t = 0; t < 2; ++t)
        #pragma unroll
        for (int n = 0; n < 4; ++n) acc2[t][n] = (f32x4){0.f, 0.f, 0.f, 0.f};

    int ar0 = wv * 32 + l16;
    #pragma unroll
    for (int ks = 0; ks < 4; ++ks) {
        bf16x8 af0 = *(const bf16x8*)&Ws[ar0 * LDA + ks * 32 + quad * 8];
        bf16x8 af1 = *(const bf16x8*)&Ws[(ar0 + 16) * LDA + ks * 32 + quad * 8];
        #pragma unroll
        for (int n = 0; n < 4; ++n) {
            bf16x8 bfr = *(const bf16x8*)&Wh[(n * 16 + l16) * 128 + ks * 32 + quad * 8];
            acc2[0][n] = __builtin_amdgcn_mfma_f32_16x16x32_bf16(af0, bfr, acc2[0][n], 0, 0, 0);
            acc2[1][n] = __builtin_amdgcn_mfma_f32_16x16x32_bf16(af1, bfr, acc2[1][n], 0, 0, 0);
        }
    }

    #pragma unroll
    for (int t = 0; t < 2; ++t) {
        #pragma unroll
        for (int n = 0; n < 4; ++n) {
            int col = n * 16 + l16;
            float b = bh[col];
            #pragma unroll
            for (int r = 0; r < 4; ++r) {
                int row = m0 + wv * 32 + t * 16 + quad * 4 + r;
                if (row < N_NODES)
                    out[(size_t)row * D_HEAD + col] = acc2[t][n][r] + b;
            }
        }
    }
}

// ---------------- launch ----------------

extern "C" void kernel_launch(void* const* d_in, const int* in_sizes, int n_in,
                              void* d_out, int out_size, void* d_ws, size_t ws_size,
                              hipStream_t stream) {
    const float* x   = (const float*)d_in[0];
    const int*   ei  = (const int*)d_in[1];
    const float* Wl0 = (const float*)d_in[2];
    const float* bl0 = (const float*)d_in[3];
    const float* Wr0 = (const float*)d_in[4];
    const float* Wl1 = (const float*)d_in[5];
    const float* bl1 = (const float*)d_in[6];
    const float* Wr1 = (const float*)d_in[7];
    const float* Wh  = (const float*)d_in[8];
    const float* bh  = (const float*)d_in[9];
    float* out = (float*)d_out;

    const int* src = ei;
    const int* dst = ei + N_EDGES;

    char* ws = (char*)d_ws;
    size_t off = 0;
    auto alloc = [&](size_t bytes) -> void* {
        void* p = ws + off;
        off += (bytes + 255) & ~(size_t)255;
        return p;
    };
    int* rowstart   = (int*)alloc((N_NODES + 1) * 4);
    int* csr        = (int*)alloc(N_EDGES * 4);
    int* bucket_cnt = (int*)alloc(NSEG * NWIN * 4);   // 32 KB

    unsigned short* Wb  = (unsigned short*)alloc((size_t)(65536 + 8192) * 2);
    unsigned short* Xb  = (unsigned short*)alloc((size_t)N_NODES * DF * 2);
    unsigned short* Ab  = (unsigned short*)alloc((size_t)N_NODES * DF * 2);
    unsigned short* H1b = (unsigned short*)alloc((size_t)N_NODES * DF * 2);

    unsigned short* Wlb0 = Wb;
    unsigned short* Wrb0 = Wb + 16384;
    unsigned short* Wlb1 = Wb + 32768;
    unsigned short* Wrb1 = Wb + 49152;
    unsigned short* Whb  = Wb + 65536;
    unsigned int* pairs  = (unsigned int*)H1b; // 10.5 MB, aliased: dead before gemm0 writes H1b

    zero_cnt_kernel<<<NSEG * NWIN / 256, 256, 0, stream>>>(bucket_cnt);

    cvt_bucket_kernel<<<NBUCK + XB + WB, 256, 0, stream>>>(
        x, Wl0, Wr0, Wl1, Wr1, Wh, src, dst, Xb, Wb, bucket_cnt, pairs);

    build_win<<<NWIN, 256, 0, stream>>>(pairs, bucket_cnt, rowstart, csr);

    // layer 0  (aggregate: 2 nodes per wave -> grid = N/8 blocks)
    aggregate_kernel<<<N_NODES / 8, 256, 0, stream>>>(Xb, rowstart, csr, Ab);
    const int grid = (N_NODES + 127) / 128;
    sage_gemm<128, true, true, true><<<grid, 256, 0, stream>>>(Ab, Xb, Wlb0, Wrb0, bl0, H1b);
    // layer 1 + head fused
    aggregate_kernel<<<N_NODES / 8, 256, 0, stream>>>(H1b, rowstart, csr, Ab);
    sage_gemm1_head<<<grid, 256, 0, stream>>>(Ab, H1b, Wlb1, Wrb1, bl1, Whb, bh, out);
}